// Round 13
// baseline (2358.034 us; speedup 1.0000x reference)
//
#include <hip/hip_runtime.h>

#define CDIM    256
#define HWDIM   1024
#define KCB     8192
#define OUT_ZQ  8388608    // B*C*H*W
#define OUT_MD  32768

// ---------------- init: zero the loss slot (d_out is poisoned before every call) ----------------
__global__ void vq_init_kernel(float* p) {
    if (threadIdx.x == 0 && blockIdx.x == 0) p[0] = 0.0f;
}

// ---------------- ||e_k||^2 : one wave per codebook row; result parked in d_out[0:8192] ----------------
__global__ __launch_bounds__(256) void vq_enorm_kernel(const float* __restrict__ emb,
                                                       float* __restrict__ enorm) {
    const int w    = threadIdx.x >> 6;
    const int lane = threadIdx.x & 63;
    const int k    = blockIdx.x * 4 + w;          // grid 2048 -> 8192 rows
    float4 v = *(const float4*)(emb + (size_t)k * CDIM + lane * 4);
    float s = v.x * v.x + v.y * v.y + v.z * v.z + v.w * v.w;
    #pragma unroll
    for (int off = 32; off > 0; off >>= 1) s += __shfl_down(s, off);
    if (lane == 0) enorm[k] = s;
}

// ---------------- fused GEMM + argmin ----------------
// 512 blocks x 512 threads (2 blocks/CU). Block = 64 queries x all 8192 codes.
// z tile (64q x 256c, 64 KB) resident in LDS for the whole kernel.
// e tile double-buffered 2 x (32c x 64k) = 16 KB, XOR-swizzled columns. Total 80 KB.
// Per thread: 2q x 4k fp32 accumulator (tx=k-group 0..15, ty=q-group 0..31).
// NCHUNK = 128 k-tiles x 8 c-chunks = 1024; decode: k-tile = t>>3, c-chunk = t&7.
__global__ __launch_bounds__(512) void vq_argmin_kernel(const float* __restrict__ z,
                                                        const float* __restrict__ emb,
                                                        const float* __restrict__ enorm,
                                                        float* __restrict__ mind_out) {
    __shared__ float zt[256][64];    // 64 KB [c][q]
    __shared__ float et[2][32][64];  // 16 KB [buf][c][ kk ^ ((c>>2)<<3) ]

    const int tid = threadIdx.x;
    const int tx  = tid & 15;        // k-group
    const int ty  = tid >> 4;        // q-group 0..31
    const int n0  = blockIdx.x * 64;
    const int b   = n0 >> 10;
    const int hw0 = n0 & 1023;
    const float* zb = z + (size_t)b * (CDIM * HWDIM) + hw0;

    // ---- stage z once: 256 rows x 16 float4 (coalesced; one-time cost)
    for (int idx = tid; idx < 256 * 16; idx += 512) {
        const int c = idx >> 4, q4 = idx & 15;
        *(float4*)&zt[c][q4 * 4] = *(const float4*)(zb + (size_t)c * HWDIM + q4 * 4);
    }

    // ---- e staging lane roles
    const int kk   = tid >> 3;       // 0..63  code within tile
    const int c4   = tid & 7;        // 0..7   float4 within 32-c chunk
    const int ecol = kk ^ (c4 << 3); // swizzled column (2-way banks both sides)

    // prologue: stage chunk 0 (k-tile 0, c-chunk 0) into buffer 0
    {
        float4 ev = *(const float4*)(emb + (size_t)kk * CDIM + c4 * 4);
        et[0][c4 * 4 + 0][ecol] = ev.x;
        et[0][c4 * 4 + 1][ecol] = ev.y;
        et[0][c4 * 4 + 2][ecol] = ev.z;
        et[0][c4 * 4 + 3][ecol] = ev.w;
    }
    __syncthreads();

    float bmin[2];
    int   bidx[2];
    #pragma unroll
    for (int i = 0; i < 2; ++i) { bmin[i] = 3.4e38f; bidx[i] = 0; }

    float acc[2][4];
    float4 en4;

    const int NCHUNK = (KCB / 64) * (CDIM / 32);   // 1024 = 128 k-tiles x 8 c-chunks
    int cur = 0;
    for (int t = 0; t < NCHUNK; ++t) {
        // T14 split: issue next chunk's global load BEFORE compute
        float4 nv;
        const bool hasnext = (t + 1) < NCHUNK;
        if (hasnext) {
            const int tn  = t + 1;
            const int nk0 = (tn >> 3) * 64;    // k-tile base (0..8128)
            const int nc0 = (tn & 7) * 32;     // c-chunk base (0..224)
            nv = *(const float4*)(emb + (size_t)(nk0 + kk) * CDIM + nc0 + c4 * 4);
        }
        if ((t & 7) == 0) {
            #pragma unroll
            for (int i = 0; i < 2; ++i)
                #pragma unroll
                for (int j = 0; j < 4; ++j) acc[i][j] = 0.0f;
            en4 = *(const float4*)(enorm + (t >> 3) * 64 + tx * 4);  // used 8 chunks later
        }
        const int c0 = (t & 7) * 32;

        // ---- compute: 32 c-steps x 8 FMA
        #pragma unroll
        for (int ci = 0; ci < 32; ++ci) {
            float2 zf = *(const float2*)&zt[c0 + ci][ty * 2];                       // broadcast read
            float4 ef = *(const float4*)&et[cur][ci][(tx * 4) ^ ((ci >> 2) << 3)];  // swizzled
            const float* zp = reinterpret_cast<const float*>(&zf);
            const float* ep = reinterpret_cast<const float*>(&ef);
            #pragma unroll
            for (int i = 0; i < 2; ++i)
                #pragma unroll
                for (int j = 0; j < 4; ++j)
                    acc[i][j] += zp[i] * ep[j];
        }

        // ---- write next chunk into the other buffer (vmcnt wait lands here, hidden)
        if (hasnext) {
            et[cur ^ 1][c4 * 4 + 0][ecol] = nv.x;
            et[cur ^ 1][c4 * 4 + 1][ecol] = nv.y;
            et[cur ^ 1][c4 * 4 + 2][ecol] = nv.z;
            et[cur ^ 1][c4 * 4 + 3][ecol] = nv.w;
        }

        // ---- epilogue every 8th chunk (full 256-c dot done): score + running argmin
        if ((t & 7) == 7) {
            const int k0 = (t >> 3) * 64;
            const float* en = reinterpret_cast<const float*>(&en4);
            #pragma unroll
            for (int j = 0; j < 4; ++j) {
                const int kid = k0 + tx * 4 + j;
                #pragma unroll
                for (int i = 0; i < 2; ++i) {
                    const float s = en[j] - 2.0f * acc[i][j];
                    if (s < bmin[i]) { bmin[i] = s; bidx[i] = kid; }
                }
            }
        }
        __syncthreads();
        cur ^= 1;
    }

    // ---- cross-tx reduction (reuse zt; safe after final barrier)
    float* redv = &zt[0][0];           // 1024 floats (zt rows 0..15)
    int*   redi = (int*)&zt[16][0];    // 1024 ints   (zt rows 16..31)
    #pragma unroll
    for (int i = 0; i < 2; ++i) {
        const int q = ty * 2 + i;
        redv[q * 16 + tx] = bmin[i];
        redi[q * 16 + tx] = bidx[i];
    }
    __syncthreads();
    if (tid < 64) {
        const int q = tid;
        float bv = redv[q * 16 + 0];
        int   bi = redi[q * 16 + 0];
        #pragma unroll
        for (int t = 1; t < 16; ++t) {
            const float v = redv[q * 16 + t];
            const int  id = redi[q * 16 + t];
            if (v < bv || (v == bv && id < bi)) { bv = v; bi = id; }
        }
        mind_out[n0 + q] = (float)bi;
    }
}

// ---------------- gather + straight-through output + loss ----------------
__global__ __launch_bounds__(256) void vq_gather_kernel(const float* __restrict__ z,
                                                        const float* __restrict__ emb,
                                                        const float* __restrict__ mind,
                                                        float* __restrict__ out,
                                                        float* __restrict__ loss_accum) {
    const int tid = blockIdx.x * 256 + threadIdx.x;
    const int total4 = OUT_ZQ / 4;
    float lsum = 0.0f;
    for (int i4 = tid; i4 < total4; i4 += gridDim.x * 256) {
        const int idx = i4 * 4;
        const int b   = idx >> 18;       // / 262144
        const int f   = idx & 262143;
        const int nn  = f >> 8;          // query index within batch
        const int cpr = f & 255;         // channel within codeword (float4-aligned)
        const int k   = (int)mind[b * 1024 + nn];
        float4 e4 = *(const float4*)(emb + (size_t)k * CDIM + cpr);
        float4 z4 = *(const float4*)(z + idx);
        float4 o;
        o.x = 2.0f * z4.x - e4.x;
        o.y = 2.0f * z4.y - e4.y;
        o.z = 2.0f * z4.z - e4.z;
        o.w = 2.0f * z4.w - e4.w;
        *(float4*)(out + idx) = o;
        const float dx = e4.x - z4.x, dy = e4.y - z4.y, dz = e4.z - z4.z, dw = e4.w - z4.w;
        lsum += dx * dx + dy * dy + dz * dz + dw * dw;
    }
    #pragma unroll
    for (int off = 32; off > 0; off >>= 1) lsum += __shfl_down(lsum, off);
    __shared__ float wsum[4];
    const int lane = threadIdx.x & 63, w = threadIdx.x >> 6;
    if (lane == 0) wsum[w] = lsum;
    __syncthreads();
    if (threadIdx.x == 0) atomicAdd(loss_accum, wsum[0] + wsum[1] + wsum[2] + wsum[3]);
}

// ---------------- finalize loss scalar (in place) ----------------
__global__ void vq_final_kernel(float* lossp) {
    if (threadIdx.x == 0 && blockIdx.x == 0)
        lossp[0] = 1.25f * lossp[0] / 8388608.0f;
}

extern "C" void kernel_launch(void* const* d_in, const int* in_sizes, int n_in,
                              void* d_out, int out_size, void* d_ws, size_t ws_size,
                              hipStream_t stream) {
    const float* z   = (const float*)d_in[0];
    const float* emb = (const float*)d_in[1];
    float* out   = (float*)d_out;
    float* mind  = out + OUT_ZQ;             // 32768 floats (min_d as float)
    float* lossp = out + OUT_ZQ + OUT_MD;    // 1 float (also the accumulation slot)
    float* enorm = out;                      // 8192 floats parked in z_q region, overwritten by gather

    vq_init_kernel<<<1, 64, 0, stream>>>(lossp);
    vq_enorm_kernel<<<2048, 256, 0, stream>>>(emb, enorm);
    vq_argmin_kernel<<<512, 512, 0, stream>>>(z, emb, enorm, mind);
    vq_gather_kernel<<<2048, 256, 0, stream>>>(z, emb, mind, out, lossp);
    vq_final_kernel<<<1, 64, 0, stream>>>(lossp);
}

// Round 14
// 1915.284 us; speedup vs baseline: 1.2312x; 1.2312x over previous
//
#include <hip/hip_runtime.h>

#define CDIM    256
#define HWDIM   1024
#define KCB     8192
#define OUT_ZQ  8388608    // B*C*H*W
#define OUT_MD  32768
#define KT      512        // 8192 codes / 16 per tile

typedef _Float16 f16x8 __attribute__((ext_vector_type(8)));
typedef float    f32x4 __attribute__((ext_vector_type(4)));

// ---------------- init: zero the loss slot ----------------
__global__ void vq_init_kernel(float* p) {
    if (threadIdx.x == 0 && blockIdx.x == 0) p[0] = 0.0f;
}

// ---------------- ||e_k||^2 (fp32, exact) -> d_out[0:8192] ----------------
__global__ __launch_bounds__(256) void vq_enorm_kernel(const float* __restrict__ emb,
                                                       float* __restrict__ enorm) {
    const int w    = threadIdx.x >> 6;
    const int lane = threadIdx.x & 63;
    const int k    = blockIdx.x * 4 + w;
    float4 v = *(const float4*)(emb + (size_t)k * CDIM + lane * 4);
    float s = v.x * v.x + v.y * v.y + v.z * v.z + v.w * v.w;
    #pragma unroll
    for (int off = 32; off > 0; off >>= 1) s += __shfl_down(s, off);
    if (lane == 0) enorm[k] = s;
}

// ---------------- pre-pass: emb fp32 -> f16 hi/lo, XOR-preswizzled rows ----------------
// Logical 16B-block x of row k stored at physical block x ^ (k&7) within the row,
// so linear LDS staging + swizzled ds_read_b128 is bank-conflict-free (rule #21).
__global__ __launch_bounds__(256) void vq_ecvt_kernel(const float* __restrict__ emb,
                                                      _Float16* __restrict__ ehi,
                                                      _Float16* __restrict__ elo) {
    const int gid = blockIdx.x * 256 + threadIdx.x;   // 262144 = 8192 rows * 32 blocks
    const int k = gid >> 5;
    const int x = gid & 31;
    const float* src = emb + (size_t)k * CDIM + x * 8;
    float4 v0 = *(const float4*)(src);
    float4 v1 = *(const float4*)(src + 4);
    const float tmp[8] = {v0.x, v0.y, v0.z, v0.w, v1.x, v1.y, v1.z, v1.w};
    f16x8 hi, lo;
    #pragma unroll
    for (int j = 0; j < 8; ++j) {
        _Float16 h = (_Float16)tmp[j];
        hi[j] = h;
        lo[j] = (_Float16)(tmp[j] - (float)h);
    }
    const int xs = x ^ (k & 7);
    *(f16x8*)(ehi + (size_t)k * CDIM + xs * 8) = hi;
    *(f16x8*)(elo + (size_t)k * CDIM + xs * 8) = lo;
}

// ---------------- MFMA argmin: split-f16 3-term (hh + hl + lh) ----------------
// 512 blocks x 128 threads (2 waves). Wave owns 2 q-tiles of 16 (block = 64 q).
// z fragments in registers (f16 hi/lo, 128 VGPR); e streamed 16 codes/tile via
// double-buffered LDS (2 x 16KB), reg-staged (T14). 6 acc chains/wave.
// Layout per verified m97 recipe: A,B lane l&15 = row, k = (l>>4)*8+j;
// D: code n = lane&15, query m = (lane>>4)*4 + reg.
__global__ __launch_bounds__(128, 1) void vq_argmin_kernel(const float* __restrict__ z,
                                                           const _Float16* __restrict__ ehi,
                                                           const _Float16* __restrict__ elo,
                                                           const float* __restrict__ enorm,
                                                           float* __restrict__ mind_out) {
    __shared__ _Float16 eb[2][2][16 * CDIM];   // [dbuf][hi/lo][16 codes * 256 c] = 32 KB

    const int tid  = threadIdx.x;
    const int lane = tid & 63;
    const int wv   = tid >> 6;          // 0..1
    const int l15  = lane & 15;
    const int l4   = lane >> 4;         // 0..3

    // ---- A fragments (z^T): coalesced 64B-per-16-lane-group reads + cvt, one-time
    f16x8 a_hi[2][8], a_lo[2][8];
    #pragma unroll
    for (int qt = 0; qt < 2; ++qt) {
        const int q0 = blockIdx.x * 64 + (wv * 2 + qt) * 16;
        const int n  = q0 + l15;
        const int b  = n >> 10;
        const int hw = n & 1023;
        const float* zb = z + (size_t)b * (CDIM * HWDIM) + hw;
        #pragma unroll
        for (int cc = 0; cc < 8; ++cc) {
            #pragma unroll
            for (int j = 0; j < 8; ++j) {
                const int c = cc * 32 + l4 * 8 + j;
                const float v = zb[(size_t)c * HWDIM];
                const _Float16 h = (_Float16)v;
                a_hi[qt][cc][j] = h;
                a_lo[qt][cc][j] = (_Float16)(v - (float)h);
            }
        }
    }

    // ---- staging: unit u (16B) -> h=u>>9, kl=(u>>5)&15, x=u&31 ; LDS linear at u*16B
    float4 greg[8];
    #pragma unroll
    for (int i = 0; i < 8; ++i) {               // load tile 0
        const int u = tid + i * 128;
        const int h = u >> 9, kl = (u >> 5) & 15, x = u & 31;
        const _Float16* g = (h ? elo : ehi) + (size_t)kl * CDIM + x * 8;
        greg[i] = *(const float4*)g;
    }
    #pragma unroll
    for (int i = 0; i < 8; ++i) {               // write tile 0 -> buf 0
        const int u = tid + i * 128;
        *(float4*)((_Float16*)eb + (size_t)u * 8) = greg[i];
    }
    #pragma unroll
    for (int i = 0; i < 8; ++i) {               // load tile 1
        const int u = tid + i * 128;
        const int h = u >> 9, kl = (u >> 5) & 15, x = u & 31;
        const _Float16* g = (h ? elo : ehi) + (size_t)(16 + kl) * CDIM + x * 8;
        greg[i] = *(const float4*)g;
    }
    __syncthreads();

    float bmin[2][4];
    int   bidx[2][4];
    #pragma unroll
    for (int qt = 0; qt < 2; ++qt)
        #pragma unroll
        for (int r = 0; r < 4; ++r) { bmin[qt][r] = 3.4e38f; bidx[qt][r] = 0; }

    const f32x4 vzero = {0.f, 0.f, 0.f, 0.f};

    for (int t = 0; t < KT; ++t) {
        const int cur = t & 1;
        const int k0  = t * 16;
        const float en = enorm[k0 + l15];       // prefetched; used after MFMAs

        f32x4 acc_hh[2], acc_hl[2], acc_lh[2];
        #pragma unroll
        for (int qt = 0; qt < 2; ++qt) { acc_hh[qt] = vzero; acc_hl[qt] = vzero; acc_lh[qt] = vzero; }

        const _Float16* ebh = &eb[cur][0][0];
        const _Float16* ebl = &eb[cur][1][0];
        #pragma unroll
        for (int cc = 0; cc < 8; ++cc) {
            const int xp = (cc * 4 + l4) ^ (l15 & 7);          // swizzled 16B block
            const f16x8 bh = *(const f16x8*)(ebh + l15 * CDIM + xp * 8);
            const f16x8 bl = *(const f16x8*)(ebl + l15 * CDIM + xp * 8);
            #pragma unroll
            for (int qt = 0; qt < 2; ++qt) {
                acc_hh[qt] = __builtin_amdgcn_mfma_f32_16x16x32_f16(a_hi[qt][cc], bh, acc_hh[qt], 0, 0, 0);
                acc_hl[qt] = __builtin_amdgcn_mfma_f32_16x16x32_f16(a_hi[qt][cc], bl, acc_hl[qt], 0, 0, 0);
                acc_lh[qt] = __builtin_amdgcn_mfma_f32_16x16x32_f16(a_lo[qt][cc], bh, acc_lh[qt], 0, 0, 0);
            }
        }

        // write staged tile t+1 into other buffer (vmcnt wait lands here, hidden)
        if (t + 1 < KT) {
            #pragma unroll
            for (int i = 0; i < 8; ++i) {
                const int u = tid + i * 128;
                *(float4*)((_Float16*)eb + (size_t)(cur ^ 1) * 8192 + (size_t)u * 8) = greg[i];
            }
        }
        // issue loads for tile t+2
        if (t + 2 < KT) {
            const int kb = (t + 2) * 16;
            #pragma unroll
            for (int i = 0; i < 8; ++i) {
                const int u = tid + i * 128;
                const int h = u >> 9, kl = (u >> 5) & 15, x = u & 31;
                const _Float16* g = (h ? elo : ehi) + (size_t)(kb + kl) * CDIM + x * 8;
                greg[i] = *(const float4*)g;
            }
        }

        // epilogue: d2 = ||e||^2 - 2*dot ; running argmin (first index wins ties)
        #pragma unroll
        for (int qt = 0; qt < 2; ++qt)
            #pragma unroll
            for (int r = 0; r < 4; ++r) {
                const float dot = acc_hh[qt][r] + acc_hl[qt][r] + acc_lh[qt][r];
                const float s = en - 2.0f * dot;
                if (s < bmin[qt][r]) { bmin[qt][r] = s; bidx[qt][r] = k0 + l15; }
            }
        __syncthreads();
    }

    // ---- cross-lane argmin over the 16 codes held per 16-lane group
    #pragma unroll
    for (int qt = 0; qt < 2; ++qt)
        #pragma unroll
        for (int r = 0; r < 4; ++r) {
            float bv = bmin[qt][r];
            int   bi = bidx[qt][r];
            #pragma unroll
            for (int m = 1; m < 16; m <<= 1) {
                const float ov = __shfl_xor(bv, m, 64);
                const int   oi = __shfl_xor(bi, m, 64);
                if (ov < bv || (ov == bv && oi < bi)) { bv = ov; bi = oi; }
            }
            if (l15 == 0) {
                const int q = blockIdx.x * 64 + (wv * 2 + qt) * 16 + l4 * 4 + r;
                mind_out[q] = (float)bi;
            }
        }
}

// ---------------- gather + straight-through output + loss (unchanged, fp32-exact) ----------------
__global__ __launch_bounds__(256) void vq_gather_kernel(const float* __restrict__ z,
                                                        const float* __restrict__ emb,
                                                        const float* __restrict__ mind,
                                                        float* __restrict__ out,
                                                        float* __restrict__ loss_accum) {
    const int tid = blockIdx.x * 256 + threadIdx.x;
    const int total4 = OUT_ZQ / 4;
    float lsum = 0.0f;
    for (int i4 = tid; i4 < total4; i4 += gridDim.x * 256) {
        const int idx = i4 * 4;
        const int b   = idx >> 18;
        const int f   = idx & 262143;
        const int nn  = f >> 8;
        const int cpr = f & 255;
        const int k   = (int)mind[b * 1024 + nn];
        float4 e4 = *(const float4*)(emb + (size_t)k * CDIM + cpr);
        float4 z4 = *(const float4*)(z + idx);
        float4 o;
        o.x = 2.0f * z4.x - e4.x;
        o.y = 2.0f * z4.y - e4.y;
        o.z = 2.0f * z4.z - e4.z;
        o.w = 2.0f * z4.w - e4.w;
        *(float4*)(out + idx) = o;
        const float dx = e4.x - z4.x, dy = e4.y - z4.y, dz = e4.z - z4.z, dw = e4.w - z4.w;
        lsum += dx * dx + dy * dy + dz * dz + dw * dw;
    }
    #pragma unroll
    for (int off = 32; off > 0; off >>= 1) lsum += __shfl_down(lsum, off);
    __shared__ float wsum[4];
    const int lane = threadIdx.x & 63, w = threadIdx.x >> 6;
    if (lane == 0) wsum[w] = lsum;
    __syncthreads();
    if (threadIdx.x == 0) atomicAdd(loss_accum, wsum[0] + wsum[1] + wsum[2] + wsum[3]);
}

// ---------------- finalize loss scalar (in place) ----------------
__global__ void vq_final_kernel(float* lossp) {
    if (threadIdx.x == 0 && blockIdx.x == 0)
        lossp[0] = 1.25f * lossp[0] / 8388608.0f;
}

extern "C" void kernel_launch(void* const* d_in, const int* in_sizes, int n_in,
                              void* d_out, int out_size, void* d_ws, size_t ws_size,
                              hipStream_t stream) {
    const float* z   = (const float*)d_in[0];
    const float* emb = (const float*)d_in[1];
    float* out   = (float*)d_out;
    float* mind  = out + OUT_ZQ;             // 32768 floats (min_d as float)
    float* lossp = out + OUT_ZQ + OUT_MD;    // 1 float (accumulation slot)
    // scratch parked in z_q region (fully overwritten by gather later):
    float*     enorm = out;                                    // 8192 f32
    _Float16*  ehi   = (_Float16*)(out + 8192);                // 8192*256 f16 = 1,048,576 floats
    _Float16*  elo   = (_Float16*)(out + 8192 + 1048576);      // same size

    vq_init_kernel<<<1, 64, 0, stream>>>(lossp);
    vq_enorm_kernel<<<2048, 256, 0, stream>>>(emb, enorm);
    vq_ecvt_kernel<<<1024, 256, 0, stream>>>(emb, ehi, elo);
    vq_argmin_kernel<<<512, 128, 0, stream>>>(z, ehi, elo, enorm, mind);
    vq_gather_kernel<<<2048, 256, 0, stream>>>(z, emb, mind, out, lossp);
    vq_final_kernel<<<1, 64, 0, stream>>>(lossp);
}